// Round 10
// baseline (136.791 us; speedup 1.0000x reference)
//
#include <hip/hip_runtime.h>
#include <hip/hip_bf16.h>

// ---- problem constants ----
#define T_DIM   2048
#define A_DIM   64
#define N_TOK   (T_DIM * A_DIM)     // 131072
#define RAWOB   120
#define N_TP    5
#define E_EXP   10
#define D_DIM   126                  // RAWOB + N_TP + 1
#define DP      128                  // padded K (row 126 = bias, row 127 = 0)
#define H_DIM   128
#define N_ACT   16
#define BTOK    256                  // contiguous tokens per block
#define NBLK    (N_TOK / BTOK)       // 512 blocks
#define LOGITS_SZ (N_TOK * N_ACT)    // 2097152

typedef __bf16 bh8 __attribute__((ext_vector_type(8)));
typedef ushort u16x8 __attribute__((ext_vector_type(8)));
typedef ushort u16x4 __attribute__((ext_vector_type(4)));
typedef short  s16x4 __attribute__((ext_vector_type(4)));
typedef float  f32x4 __attribute__((ext_vector_type(4)));

__device__ __forceinline__ f32x4 mfma16(bh8 a, bh8 b, f32x4 c) {
    return __builtin_amdgcn_mfma_f32_16x16x32_bf16(a, b, c, 0, 0, 0);
}
// K=16 variant: per-lane k-quads (k = 4*lq + j) — matches swapped-L1 output layout
__device__ __forceinline__ f32x4 mfma16k16(s16x4 a, s16x4 b, f32x4 c) {
    return __builtin_amdgcn_mfma_f32_16x16x16bf16_1k(a, b, c, 0, 0, 0);
}

__device__ __forceinline__ ushort f2bf(float f) {
    unsigned x = __builtin_bit_cast(unsigned, f);
    unsigned r = (x + 0x7fffu + ((x >> 16) & 1u)) >> 16;   // round-nearest-even
    return (ushort)r;
}

#define W1P_N (E_EXP * H_DIM * DP)           // 163840 ushorts
#define W2P_N (E_EXP * N_ACT * H_DIM)        // 20480
#define WC1P_N (DP * DP)                     // 16384

// ---------------- kernel 0: weight packing only ----------------
#define PB_BLOCKS 124

__global__ __launch_bounds__(256) void prep_kernel(
    const float* __restrict__ W1, const float* __restrict__ W2,
    const float* __restrict__ Wc1, const float* __restrict__ b1,
    const float* __restrict__ bc1,
    ushort* __restrict__ W1p, ushort* __restrict__ W2p, ushort* __restrict__ Wc1p)
{
    int bx = blockIdx.x, tid = threadIdx.x;
    if (bx < 44) {
        __shared__ ushort st[32][130];   // 32 d-rows x 128 n, padded
        const float* src;
        const float* bias;
        ushort* dstbase;
        int kt;
        if (bx < 40) {                   // W1: e = bx>>2, kt = bx&3
            int e = bx >> 2;
            kt = bx & 3;
            src = W1 + (e * D_DIM + kt * 32) * H_DIM;
            bias = b1 + e * H_DIM;
            dstbase = W1p + e * (H_DIM * DP);
        } else {                         // Wc1: kt = bx-40
            kt = bx - 40;
            src = Wc1 + kt * 32 * H_DIM;
            bias = bc1;
            dstbase = Wc1p;
        }
        int dmax = D_DIM - kt * 32;      // 32,32,32,30
#pragma unroll
        for (int p = 0; p < 16; ++p) {
            int idx = p * 256 + tid;
            int dd = idx >> 7, n = idx & 127;
            float v;
            if (dd < dmax)                    v = src[dd * H_DIM + n];   // coalesced in n
            else if (kt == 3 && dd == 30)     v = bias[n];               // bias row (k=126)
            else                              v = 0.f;                   // k=127 pad
            st[dd][n] = f2bf(v);
        }
        __syncthreads();
#pragma unroll
        for (int p = 0; p < 16; ++p) {
            int idx = p * 256 + tid;
            int dd = idx >> 7, n = idx & 127;
            // frag position: nt=n>>4, lm=n&15, lq=dd>>3, j=dd&7
            dstbase[((n >> 4) * 4 + kt) * 512 + ((dd >> 3) * 16 + (n & 15)) * 8 + (dd & 7)]
                = st[dd][n];
        }
    } else {
        // W2 packed as 16x16x16 B-frags: tile kk (k = kk*16 + 4*lq + j), col = lm
        int i = (bx - 44) * 256 + tid;   // [0, 20480)
        int e   = i >> 11;
        int rem = i & 2047;
        int kk  = rem >> 8;
        int idx = rem & 255;
        int l = idx >> 2, j = idx & 3;
        int lq = l >> 4, lm = l & 15;
        W2p[i] = f2bf(W2[(e * H_DIM + kk * 16 + lq * 4 + j) * N_ACT + lm]);
    }
}

// npair for a bucket of c tokens: pair-of-16-row-tiles jobs
#define NPAIR(c) (((((c) + 15) >> 4) + 1) >> 1)

// ---------------- kernel 1: natural-order fused MoE + critic ------------------
// R9 structure (best: 132.1 total) + three micro-opts:
//  1. kt-split accumulators: 4 independent MFMA chains per pair-job (half the
//     dependent critical path at 4 waves/SIMD residency).
//  2. explicit 1-nt-ahead weight prefetch (rotating regs, static unroll) — at
//     52 VGPR / 128 cap the compiler wasn't pipelining across nt steps.
//  3. no serial tid0 layout: every thread derives job->(expert,slotbase) from
//     lc[] via unrolled prefix scan; one barrier fewer.
__global__ __launch_bounds__(512, 4) void moe_kernel(
    const float* __restrict__ obs, const int* __restrict__ pick,
    const int* __restrict__ hete_type, const int* __restrict__ gp_sel,
    const float* __restrict__ b2, const float* __restrict__ bc2,
    const ushort* __restrict__ W1p, const ushort* __restrict__ W2p,
    const ushort* __restrict__ Wc1p, const float* __restrict__ Wc2,
    float* __restrict__ out)
{
    __shared__ __align__(16) ushort xa[BTOK * 128];   // 64KB swizzled bf16 rows
    __shared__ short map[576];                        // padded slot -> local token
    __shared__ int lc[16];

    const int bx  = blockIdx.x;
    const int tid = threadIdx.x;
    const int gbase = bx * BTOK;

    if (tid < 16) lc[tid] = 0;
    for (int i = tid; i < 576; i += 512) map[i] = -1;
    __syncthreads();

    // ---- local bucket count (threads 0..255, one token each) ----
    int mye = 0, myloc = 0;
    if (tid < BTOK) {
        mye = pick[gbase + tid];
        myloc = atomicAdd(&lc[mye], 1);
    }

    // ---- stage obs -> LDS bf16, granule-swizzled; fully coalesced global ----
#pragma unroll
    for (int p = 0; p < 8; ++p) {
        int idx = p * 512 + tid;
        if (idx < BTOK * 15) {
            int r = idx / 15, g = idx - r * 15;
            const float* s = obs + (size_t)(gbase + r) * RAWOB + g * 8;
            float4 u0 = *(const float4*)(const void*)s;
            float4 u1 = *(const float4*)(const void*)(s + 4);
            u16x8 t;
            t[0] = f2bf(u0.x); t[1] = f2bf(u0.y); t[2] = f2bf(u0.z); t[3] = f2bf(u0.w);
            t[4] = f2bf(u1.x); t[5] = f2bf(u1.y); t[6] = f2bf(u1.z); t[7] = f2bf(u1.w);
            *(u16x8*)(void*)(xa + r * 128 + (g ^ (r & 15)) * 8) = t;
        }
    }
    // augment granule 15: [hete_type, gp_obs(5), 1.0 (bias k=126), 0]
    if (tid < BTOK) {
        int tok = gbase + tid;
        int ht = hete_type[tok];
        int tt = tok >> 6;                  // token / A_DIM
        u16x8 t;
        t[0] = f2bf((float)ht);
#pragma unroll
        for (int q = 0; q < N_TP; ++q) {
            float g = (q == ht) ? -1.0f : (float)gp_sel[tt * N_TP + q];
            t[1 + q] = f2bf(g);
        }
        t[6] = (ushort)0x3F80;              // 1.0 -> picks up bias row 126
        t[7] = 0;
        *(u16x8*)(void*)(xa + tid * 128 + (15 ^ (tid & 15)) * 8) = t;
    }
    __syncthreads();   // lc final + xa staged

    // ---- every thread derives the job layout from lc (no serial section) ----
    int cnt[10], np[10];
#pragma unroll
    for (int e = 0; e < E_EXP; ++e) { cnt[e] = lc[e]; np[e] = NPAIR(cnt[e]); }
    // slot base for this thread's own expert (for map write)
    int lb = 0;
#pragma unroll
    for (int e = 0; e < E_EXP - 1; ++e) lb += (mye > e) ? np[e] * 32 : 0;
    if (tid < BTOK) map[lb + myloc] = (short)tid;
    int NJ = 0;
#pragma unroll
    for (int e = 0; e < E_EXP; ++e) NJ += np[e];
    __syncthreads();   // map ready

    const int w = tid >> 6;
    const int l = tid & 63;
    const int lm = l & 15;
    const int lq = l >> 4;
    const float bcv = bc2[0];

    // ---- expert path: waves grab PAIR jobs round-robin; weights from L2 ----
    for (int i = w; i < NJ; i += 8) {
        // decode job -> (expert e, slot base tb) via unrolled prefix scan
        int e = 0, tb = 0, pj = 0, ps = 0;
#pragma unroll
        for (int q = 0; q < E_EXP; ++q) {
            bool hit = (i >= pj) && (i < pj + np[q]);
            if (hit) { e = q; tb = ps + (i - pj) * 32; }
            pj += np[q];
            ps += np[q] * 32;
        }
        const int m0 = map[tb + lm];
        const int m1 = map[tb + 16 + lm];
        const int row0 = m0 < 0 ? 0 : m0;
        const int row1 = m1 < 0 ? 0 : m1;
        bh8 a0[4], a1[4];
#pragma unroll
        for (int kt = 0; kt < 4; ++kt) {
            int g = kt * 4 + lq;
            a0[kt] = *(const bh8*)(const void*)(xa + row0 * 128 + (g ^ (row0 & 15)) * 8);
            a1[kt] = *(const bh8*)(const void*)(xa + row1 * 128 + (g ^ (row1 & 15)) * 8);
        }
        const ushort* w1e = W1p + e * (H_DIM * DP);
        const ushort* w2e = W2p + e * 2048;
        const float bb = b2[e * N_ACT + lm];
        f32x4 y0 = (f32x4){0.f, 0.f, 0.f, 0.f};
        f32x4 y1 = (f32x4){0.f, 0.f, 0.f, 0.f};
        // preload nt=0 weight fragments; rotate 1-nt-ahead inside the loop
        bh8 wf0 = *(const bh8*)(const void*)(w1e + 0 * 512 + l * 8);
        bh8 wf1 = *(const bh8*)(const void*)(w1e + 1 * 512 + l * 8);
        bh8 wf2 = *(const bh8*)(const void*)(w1e + 2 * 512 + l * 8);
        bh8 wf3 = *(const bh8*)(const void*)(w1e + 3 * 512 + l * 8);
#pragma unroll
        for (int nt = 0; nt < 8; ++nt) {
            bh8 nf0 = wf0, nf1 = wf1, nf2 = wf2, nf3 = wf3;
            if (nt < 7) {   // prefetch next nt's fragments (static unroll)
                nf0 = *(const bh8*)(const void*)(w1e + ((nt + 1) * 4 + 0) * 512 + l * 8);
                nf1 = *(const bh8*)(const void*)(w1e + ((nt + 1) * 4 + 1) * 512 + l * 8);
                nf2 = *(const bh8*)(const void*)(w1e + ((nt + 1) * 4 + 2) * 512 + l * 8);
                nf3 = *(const bh8*)(const void*)(w1e + ((nt + 1) * 4 + 3) * 512 + l * 8);
            }
            // kt-split: 4 independent depth-2 MFMA chains
            f32x4 z = (f32x4){0.f, 0.f, 0.f, 0.f};
            f32x4 p0a = mfma16(wf0, a0[0], z), p0b = mfma16(wf2, a0[2], z);
            f32x4 p1a = mfma16(wf0, a1[0], z), p1b = mfma16(wf2, a1[2], z);
            p0a = mfma16(wf1, a0[1], p0a);  p0b = mfma16(wf3, a0[3], p0b);
            p1a = mfma16(wf1, a1[1], p1a);  p1b = mfma16(wf3, a1[3], p1b);
            f32x4 ae0 = p0a + p0b;
            f32x4 ae1 = p1a + p1b;
            u16x4 hp0, hp1;
#pragma unroll
            for (int r = 0; r < 4; ++r) {
                hp0[r] = f2bf(fmaxf(ae0[r], 0.f));
                hp1[r] = f2bf(fmaxf(ae1[r], 0.f));
            }
            s16x4 w2f = *(const s16x4*)(const void*)(w2e + nt * 256 + l * 4);
            y0 = mfma16k16(__builtin_bit_cast(s16x4, hp0), w2f, y0);
            y1 = mfma16k16(__builtin_bit_cast(s16x4, hp1), w2f, y1);
            wf0 = nf0; wf1 = nf1; wf2 = nf2; wf3 = nf3;
        }
#pragma unroll
        for (int r = 0; r < 4; ++r) {
            int s0 = map[tb + lq * 4 + r];
            if (s0 >= 0) out[(size_t)(gbase + s0) * N_ACT + lm] = y0[r] + bb;
            int s1 = map[tb + 16 + lq * 4 + r];
            if (s1 >= 0) out[(size_t)(gbase + s1) * N_ACT + lm] = y1[r] + bb;
        }
    }

    // ---- critic: natural-order rows, 2 m-frags/fragment, kt-split chains ----
    {
        const int r0 = w * 32;
        const int row0 = r0 + lm, row1 = r0 + 16 + lm;
        bh8 a0[4], a1[4];
#pragma unroll
        for (int kt = 0; kt < 4; ++kt) {
            int g = kt * 4 + lq;
            a0[kt] = *(const bh8*)(const void*)(xa + row0 * 128 + (g ^ (row0 & 15)) * 8);
            a1[kt] = *(const bh8*)(const void*)(xa + row1 * 128 + (g ^ (row1 & 15)) * 8);
        }
        float p0 = 0.f, p1 = 0.f;
        bh8 wf0 = *(const bh8*)(const void*)(Wc1p + 0 * 512 + l * 8);
        bh8 wf1 = *(const bh8*)(const void*)(Wc1p + 1 * 512 + l * 8);
        bh8 wf2 = *(const bh8*)(const void*)(Wc1p + 2 * 512 + l * 8);
        bh8 wf3 = *(const bh8*)(const void*)(Wc1p + 3 * 512 + l * 8);
#pragma unroll
        for (int nt = 0; nt < 8; ++nt) {
            bh8 nf0 = wf0, nf1 = wf1, nf2 = wf2, nf3 = wf3;
            if (nt < 7) {
                nf0 = *(const bh8*)(const void*)(Wc1p + ((nt + 1) * 4 + 0) * 512 + l * 8);
                nf1 = *(const bh8*)(const void*)(Wc1p + ((nt + 1) * 4 + 1) * 512 + l * 8);
                nf2 = *(const bh8*)(const void*)(Wc1p + ((nt + 1) * 4 + 2) * 512 + l * 8);
                nf3 = *(const bh8*)(const void*)(Wc1p + ((nt + 1) * 4 + 3) * 512 + l * 8);
            }
            f32x4 z = (f32x4){0.f, 0.f, 0.f, 0.f};
            f32x4 c0a = mfma16(wf0, a0[0], z), c0b = mfma16(wf2, a0[2], z);
            f32x4 c1a = mfma16(wf0, a1[0], z), c1b = mfma16(wf2, a1[2], z);
            c0a = mfma16(wf1, a0[1], c0a);  c0b = mfma16(wf3, a0[3], c0b);
            c1a = mfma16(wf1, a1[1], c1a);  c1b = mfma16(wf3, a1[3], c1b);
            f32x4 c0 = c0a + c0b;
            f32x4 c1 = c1a + c1b;
            const float4 wc = *(const float4*)(const void*)(Wc2 + nt * 16 + lq * 4);
            p0 += fmaxf(c0[0], 0.f) * wc.x + fmaxf(c0[1], 0.f) * wc.y
                + fmaxf(c0[2], 0.f) * wc.z + fmaxf(c0[3], 0.f) * wc.w;
            p1 += fmaxf(c1[0], 0.f) * wc.x + fmaxf(c1[1], 0.f) * wc.y
                + fmaxf(c1[2], 0.f) * wc.z + fmaxf(c1[3], 0.f) * wc.w;
            wf0 = nf0; wf1 = nf1; wf2 = nf2; wf3 = nf3;
        }
        // lane (lq,lm) holds token's partial over its n-subset; sum over lq
        p0 += __shfl_xor(p0, 16, 64); p0 += __shfl_xor(p0, 32, 64);
        p1 += __shfl_xor(p1, 16, 64); p1 += __shfl_xor(p1, 32, 64);
        if (lq == 0) {
            out[LOGITS_SZ + gbase + row0] = p0 + bcv;
            out[LOGITS_SZ + gbase + row1] = p1 + bcv;
        }
    }
}

extern "C" void kernel_launch(void* const* d_in, const int* in_sizes, int n_in,
                              void* d_out, int out_size, void* d_ws, size_t ws_size,
                              hipStream_t stream) {
    const float* obs  = (const float*)d_in[0];
    const int*   pick = (const int*)d_in[1];
    const int*   htyp = (const int*)d_in[2];
    const int*   gp   = (const int*)d_in[3];
    const float* W1   = (const float*)d_in[4];
    const float* b1   = (const float*)d_in[5];
    const float* W2   = (const float*)d_in[6];
    const float* b2   = (const float*)d_in[7];
    const float* Wc1  = (const float*)d_in[8];
    const float* bc1  = (const float*)d_in[9];
    const float* Wc2  = (const float*)d_in[10];
    const float* bc2  = (const float*)d_in[11];
    float* out = (float*)d_out;

    ushort* W1p  = (ushort*)d_ws;
    ushort* W2p  = W1p + W1P_N;
    ushort* Wc1p = W2p + W2P_N;

    prep_kernel<<<PB_BLOCKS, 256, 0, stream>>>(
        W1, W2, Wc1, b1, bc1, W1p, W2p, Wc1p);
    moe_kernel<<<NBLK, 512, 0, stream>>>(
        obs, pick, htyp, gp, b2, bc2,
        W1p, W2p, Wc1p, Wc2, out);
}

// Round 11
// 136.561 us; speedup vs baseline: 1.0017x; 1.0017x over previous
//
#include <hip/hip_runtime.h>
#include <hip/hip_bf16.h>

// ---- problem constants ----
#define T_DIM   2048
#define A_DIM   64
#define N_TOK   (T_DIM * A_DIM)     // 131072
#define RAWOB   120
#define N_TP    5
#define E_EXP   10
#define D_DIM   126                  // RAWOB + N_TP + 1
#define DP      128                  // padded K (row 126 = bias, row 127 = 0)
#define H_DIM   128
#define N_ACT   16
#define BTOK    256                  // contiguous tokens per block
#define NBLK    (N_TOK / BTOK)       // 512 blocks
#define LOGITS_SZ (N_TOK * N_ACT)    // 2097152

typedef __bf16 bh8 __attribute__((ext_vector_type(8)));
typedef ushort u16x8 __attribute__((ext_vector_type(8)));
typedef ushort u16x4 __attribute__((ext_vector_type(4)));
typedef short  s16x4 __attribute__((ext_vector_type(4)));
typedef float  f32x4 __attribute__((ext_vector_type(4)));

__device__ __forceinline__ f32x4 mfma16(bh8 a, bh8 b, f32x4 c) {
    return __builtin_amdgcn_mfma_f32_16x16x32_bf16(a, b, c, 0, 0, 0);
}
// K=16 variant: per-lane k-quads (k = 4*lq + j) — matches swapped-L1 output layout
__device__ __forceinline__ f32x4 mfma16k16(s16x4 a, s16x4 b, f32x4 c) {
    return __builtin_amdgcn_mfma_f32_16x16x16bf16_1k(a, b, c, 0, 0, 0);
}

__device__ __forceinline__ ushort f2bf(float f) {
    unsigned x = __builtin_bit_cast(unsigned, f);
    unsigned r = (x + 0x7fffu + ((x >> 16) & 1u)) >> 16;   // round-nearest-even
    return (ushort)r;
}

#define W1P_N (E_EXP * H_DIM * DP)           // 163840 ushorts
#define W2P_N (E_EXP * N_ACT * H_DIM)        // 20480
#define WC1P_N (DP * DP)                     // 16384

// ---------------- kernel 0: weight packing only ----------------
#define PB_BLOCKS 124

__global__ __launch_bounds__(256) void prep_kernel(
    const float* __restrict__ W1, const float* __restrict__ W2,
    const float* __restrict__ Wc1, const float* __restrict__ b1,
    const float* __restrict__ bc1,
    ushort* __restrict__ W1p, ushort* __restrict__ W2p, ushort* __restrict__ Wc1p)
{
    int bx = blockIdx.x, tid = threadIdx.x;
    if (bx < 44) {
        __shared__ ushort st[32][130];   // 32 d-rows x 128 n, padded
        const float* src;
        const float* bias;
        ushort* dstbase;
        int kt;
        if (bx < 40) {                   // W1: e = bx>>2, kt = bx&3
            int e = bx >> 2;
            kt = bx & 3;
            src = W1 + (e * D_DIM + kt * 32) * H_DIM;
            bias = b1 + e * H_DIM;
            dstbase = W1p + e * (H_DIM * DP);
        } else {                         // Wc1: kt = bx-40
            kt = bx - 40;
            src = Wc1 + kt * 32 * H_DIM;
            bias = bc1;
            dstbase = Wc1p;
        }
        int dmax = D_DIM - kt * 32;      // 32,32,32,30
#pragma unroll
        for (int p = 0; p < 16; ++p) {
            int idx = p * 256 + tid;
            int dd = idx >> 7, n = idx & 127;
            float v;
            if (dd < dmax)                    v = src[dd * H_DIM + n];   // coalesced in n
            else if (kt == 3 && dd == 30)     v = bias[n];               // bias row (k=126)
            else                              v = 0.f;                   // k=127 pad
            st[dd][n] = f2bf(v);
        }
        __syncthreads();
#pragma unroll
        for (int p = 0; p < 16; ++p) {
            int idx = p * 256 + tid;
            int dd = idx >> 7, n = idx & 127;
            // frag position: nt=n>>4, lm=n&15, lq=dd>>3, j=dd&7
            dstbase[((n >> 4) * 4 + kt) * 512 + ((dd >> 3) * 16 + (n & 15)) * 8 + (dd & 7)]
                = st[dd][n];
        }
    } else {
        // W2 packed as 16x16x16 B-frags: tile kk (k = kk*16 + 4*lq + j), col = lm
        int i = (bx - 44) * 256 + tid;   // [0, 20480)
        int e   = i >> 11;
        int rem = i & 2047;
        int kk  = rem >> 8;
        int idx = rem & 255;
        int l = idx >> 2, j = idx & 3;
        int lq = l >> 4, lm = l & 15;
        W2p[i] = f2bf(W2[(e * H_DIM + kk * 16 + lq * 4 + j) * N_ACT + lm]);
    }
}

// ---------------- kernel 1: natural-order fused MoE + critic ------------------
// R9 structure verbatim (best: 132.1 total; VGPR 52, no spill) with ONE change:
// 1024 threads (16 waves) per 256-token tile. Same LDS (67KB -> 2 blocks/CU),
// same inner loops, same per-token weight traffic — but 32 waves/CU instead of
// 16 to hide the per-nt L2 weight latency. Expert pair-jobs stride 16 across
// waves (NJ~10-15 so most waves run <=1 job); critic on waves 8-15 (2-frag Wc1
// sharing, L2 traffic unchanged). No barrier between phases: idle waves start
// the critic while job-waves compute.
__global__ __launch_bounds__(1024, 4) void moe_kernel(
    const float* __restrict__ obs, const int* __restrict__ pick,
    const int* __restrict__ hete_type, const int* __restrict__ gp_sel,
    const float* __restrict__ b2, const float* __restrict__ bc2,
    const ushort* __restrict__ W1p, const ushort* __restrict__ W2p,
    const ushort* __restrict__ Wc1p, const float* __restrict__ Wc2,
    float* __restrict__ out)
{
    __shared__ __align__(16) ushort xa[BTOK * 128];   // 64KB swizzled bf16 rows
    __shared__ short map[576];                        // padded slot -> local token
    __shared__ short jexp[24];                        // job -> expert
    __shared__ short jtb[24];                         // job -> slot base (pair = 32 slots)
    __shared__ int lc[16], lbase[16];
    __shared__ int nj_tot;

    const int bx  = blockIdx.x;
    const int tid = threadIdx.x;
    const int gbase = bx * BTOK;

    if (tid < 16) lc[tid] = 0;
    for (int i = tid; i < 576; i += 1024) map[i] = -1;
    __syncthreads();

    // ---- local bucket count (threads 0..255, one token each) ----
    int mye = 0, myloc = 0;
    if (tid < BTOK) {
        mye = pick[gbase + tid];
        myloc = atomicAdd(&lc[mye], 1);
    }

    // ---- stage obs -> LDS bf16, granule-swizzled; fully coalesced global ----
    // idx in [0,3840): row r = idx/15, granule g = idx%15 (8 floats -> 16B bf16)
#pragma unroll
    for (int p = 0; p < 4; ++p) {
        int idx = p * 1024 + tid;
        if (idx < BTOK * 15) {
            int r = idx / 15, g = idx - r * 15;
            const float* s = obs + (size_t)(gbase + r) * RAWOB + g * 8;
            float4 u0 = *(const float4*)(const void*)s;
            float4 u1 = *(const float4*)(const void*)(s + 4);
            u16x8 t;
            t[0] = f2bf(u0.x); t[1] = f2bf(u0.y); t[2] = f2bf(u0.z); t[3] = f2bf(u0.w);
            t[4] = f2bf(u1.x); t[5] = f2bf(u1.y); t[6] = f2bf(u1.z); t[7] = f2bf(u1.w);
            *(u16x8*)(void*)(xa + r * 128 + (g ^ (r & 15)) * 8) = t;
        }
    }
    // augment granule 15: [hete_type, gp_obs(5), 1.0 (bias k=126), 0]
    if (tid < BTOK) {
        int tok = gbase + tid;
        int ht = hete_type[tok];
        int tt = tok >> 6;                  // token / A_DIM
        u16x8 t;
        t[0] = f2bf((float)ht);
#pragma unroll
        for (int q = 0; q < N_TP; ++q) {
            float g = (q == ht) ? -1.0f : (float)gp_sel[tt * N_TP + q];
            t[1 + q] = f2bf(g);
        }
        t[6] = (ushort)0x3F80;              // 1.0 -> picks up bias row 126
        t[7] = 0;
        *(u16x8*)(void*)(xa + tid * 128 + (15 ^ (tid & 15)) * 8) = t;
    }
    __syncthreads();

    // ---- serial job layout: pair-of-tiles (32 slots) per job ----
    if (tid == 0) {
        int pb = 0, nj = 0;
#pragma unroll
        for (int e = 0; e < E_EXP; ++e) {
            lbase[e] = pb;
            int ntile = (lc[e] + 15) >> 4;          // tiles of 16
            int npair = (ntile + 1) >> 1;           // pad odd -> pair
            for (int k = 0; k < npair; ++k) {
                jexp[nj] = (short)e;
                jtb[nj]  = (short)(pb + k * 32);
                ++nj;
            }
            pb += npair * 32;
        }
        nj_tot = nj;
    }
    __syncthreads();
    if (tid < BTOK) map[lbase[mye] + myloc] = (short)tid;
    __syncthreads();

    const int w = tid >> 6;                 // 0..15
    const int l = tid & 63;
    const int lm = l & 15;
    const int lq = l >> 4;
    const float bcv = bc2[0];

    // ---- expert path: 16 waves grab PAIR jobs round-robin; weights from L2 ----
    const int NJ = nj_tot;
    for (int i = w; i < NJ; i += 16) {
        const int e  = jexp[i];
        const int tb = jtb[i];
        const int m0 = map[tb + lm];
        const int m1 = map[tb + 16 + lm];
        const int row0 = m0 < 0 ? 0 : m0;
        const int row1 = m1 < 0 ? 0 : m1;
        bh8 a0[4], a1[4];
#pragma unroll
        for (int kt = 0; kt < 4; ++kt) {
            int g = kt * 4 + lq;
            a0[kt] = *(const bh8*)(const void*)(xa + row0 * 128 + (g ^ (row0 & 15)) * 8);
            a1[kt] = *(const bh8*)(const void*)(xa + row1 * 128 + (g ^ (row1 & 15)) * 8);
        }
        const ushort* w1e = W1p + e * (H_DIM * DP);
        const ushort* w2e = W2p + e * 2048;
        const float bb = b2[e * N_ACT + lm];
        f32x4 y0 = (f32x4){0.f, 0.f, 0.f, 0.f};
        f32x4 y1 = (f32x4){0.f, 0.f, 0.f, 0.f};
#pragma unroll
        for (int nt = 0; nt < 8; ++nt) {
            f32x4 ae0 = (f32x4){0.f, 0.f, 0.f, 0.f}, ae1 = ae0;
#pragma unroll
            for (int kt = 0; kt < 4; ++kt) {
                bh8 wf = *(const bh8*)(const void*)(w1e + (nt * 4 + kt) * 512 + l * 8);
                ae0 = mfma16(wf, a0[kt], ae0);          // two independent chains
                ae1 = mfma16(wf, a1[kt], ae1);          // per weight fragment
            }
            u16x4 hp0, hp1;
#pragma unroll
            for (int r = 0; r < 4; ++r) {
                hp0[r] = f2bf(fmaxf(ae0[r], 0.f));
                hp1[r] = f2bf(fmaxf(ae1[r], 0.f));
            }
            s16x4 w2f = *(const s16x4*)(const void*)(w2e + nt * 256 + l * 4);
            y0 = mfma16k16(__builtin_bit_cast(s16x4, hp0), w2f, y0);
            y1 = mfma16k16(__builtin_bit_cast(s16x4, hp1), w2f, y1);
        }
#pragma unroll
        for (int r = 0; r < 4; ++r) {
            int s0 = map[tb + lq * 4 + r];
            if (s0 >= 0) out[(size_t)(gbase + s0) * N_ACT + lm] = y0[r] + bb;
            int s1 = map[tb + 16 + lq * 4 + r];
            if (s1 >= 0) out[(size_t)(gbase + s1) * N_ACT + lm] = y1[r] + bb;
        }
    }

    // ---- critic on waves 8..15: 2 m-frags per Wc1 fragment (traffic = R9) ----
    if (w >= 8) {
        const int r0 = (w - 8) * 32;
        const int row0 = r0 + lm, row1 = r0 + 16 + lm;
        bh8 a0[4], a1[4];
#pragma unroll
        for (int kt = 0; kt < 4; ++kt) {
            int g = kt * 4 + lq;
            a0[kt] = *(const bh8*)(const void*)(xa + row0 * 128 + (g ^ (row0 & 15)) * 8);
            a1[kt] = *(const bh8*)(const void*)(xa + row1 * 128 + (g ^ (row1 & 15)) * 8);
        }
        float p0 = 0.f, p1 = 0.f;
#pragma unroll
        for (int nt = 0; nt < 8; ++nt) {
            f32x4 c0 = (f32x4){0.f,0.f,0.f,0.f}, c1 = c0;
#pragma unroll
            for (int kt = 0; kt < 4; ++kt) {
                bh8 wf = *(const bh8*)(const void*)(Wc1p + (nt * 4 + kt) * 512 + l * 8);
                c0 = mfma16(wf, a0[kt], c0);
                c1 = mfma16(wf, a1[kt], c1);
            }
            const float4 wc = *(const float4*)(const void*)(Wc2 + nt * 16 + lq * 4);
            p0 += fmaxf(c0[0], 0.f) * wc.x + fmaxf(c0[1], 0.f) * wc.y
                + fmaxf(c0[2], 0.f) * wc.z + fmaxf(c0[3], 0.f) * wc.w;
            p1 += fmaxf(c1[0], 0.f) * wc.x + fmaxf(c1[1], 0.f) * wc.y
                + fmaxf(c1[2], 0.f) * wc.z + fmaxf(c1[3], 0.f) * wc.w;
        }
        // lane (lq,lm) holds token's partial over its n-subset; sum over lq
        p0 += __shfl_xor(p0, 16, 64); p0 += __shfl_xor(p0, 32, 64);
        p1 += __shfl_xor(p1, 16, 64); p1 += __shfl_xor(p1, 32, 64);
        if (lq == 0) {
            out[LOGITS_SZ + gbase + row0] = p0 + bcv;
            out[LOGITS_SZ + gbase + row1] = p1 + bcv;
        }
    }
}

extern "C" void kernel_launch(void* const* d_in, const int* in_sizes, int n_in,
                              void* d_out, int out_size, void* d_ws, size_t ws_size,
                              hipStream_t stream) {
    const float* obs  = (const float*)d_in[0];
    const int*   pick = (const int*)d_in[1];
    const int*   htyp = (const int*)d_in[2];
    const int*   gp   = (const int*)d_in[3];
    const float* W1   = (const float*)d_in[4];
    const float* b1   = (const float*)d_in[5];
    const float* W2   = (const float*)d_in[6];
    const float* b2   = (const float*)d_in[7];
    const float* Wc1  = (const float*)d_in[8];
    const float* bc1  = (const float*)d_in[9];
    const float* Wc2  = (const float*)d_in[10];
    const float* bc2  = (const float*)d_in[11];
    float* out = (float*)d_out;

    ushort* W1p  = (ushort*)d_ws;
    ushort* W2p  = W1p + W1P_N;
    ushort* Wc1p = W2p + W2P_N;

    prep_kernel<<<PB_BLOCKS, 256, 0, stream>>>(
        W1, W2, Wc1, b1, bc1, W1p, W2p, Wc1p);
    moe_kernel<<<NBLK, 1024, 0, stream>>>(
        obs, pick, htyp, gp, b2, bc2,
        W1p, W2p, Wc1p, Wc2, out);
}

// Round 12
// 131.170 us; speedup vs baseline: 1.0428x; 1.0411x over previous
//
#include <hip/hip_runtime.h>
#include <hip/hip_bf16.h>

// ---- problem constants ----
#define T_DIM   2048
#define A_DIM   64
#define N_TOK   (T_DIM * A_DIM)     // 131072
#define RAWOB   120
#define N_TP    5
#define E_EXP   10
#define D_DIM   126                  // RAWOB + N_TP + 1
#define DP      128                  // padded K (row 126 = bias, row 127 = 0)
#define H_DIM   128
#define N_ACT   16
#define BTOK    256                  // contiguous tokens per block
#define NBLK    (N_TOK / BTOK)       // 512 blocks
#define LOGITS_SZ (N_TOK * N_ACT)    // 2097152

typedef __bf16 bh8 __attribute__((ext_vector_type(8)));
typedef ushort u16x8 __attribute__((ext_vector_type(8)));
typedef ushort u16x4 __attribute__((ext_vector_type(4)));
typedef short  s16x4 __attribute__((ext_vector_type(4)));
typedef float  f32x4 __attribute__((ext_vector_type(4)));

__device__ __forceinline__ f32x4 mfma16(bh8 a, bh8 b, f32x4 c) {
    return __builtin_amdgcn_mfma_f32_16x16x32_bf16(a, b, c, 0, 0, 0);
}
// K=16 variant: per-lane k-quads (k = 4*lq + j) — matches swapped-L1 output layout
__device__ __forceinline__ f32x4 mfma16k16(s16x4 a, s16x4 b, f32x4 c) {
    return __builtin_amdgcn_mfma_f32_16x16x16bf16_1k(a, b, c, 0, 0, 0);
}

__device__ __forceinline__ ushort f2bf(float f) {
    unsigned x = __builtin_bit_cast(unsigned, f);
    unsigned r = (x + 0x7fffu + ((x >> 16) & 1u)) >> 16;   // round-nearest-even
    return (ushort)r;
}

#define W1P_N (E_EXP * H_DIM * DP)           // 163840 ushorts
#define W2P_N (E_EXP * N_ACT * H_DIM)        // 20480
#define WC1P_N (DP * DP)                     // 16384

// ---------------- kernel 0: weight packing only ----------------
#define PB_BLOCKS 124

__global__ __launch_bounds__(256) void prep_kernel(
    const float* __restrict__ W1, const float* __restrict__ W2,
    const float* __restrict__ Wc1, const float* __restrict__ b1,
    const float* __restrict__ bc1,
    ushort* __restrict__ W1p, ushort* __restrict__ W2p, ushort* __restrict__ Wc1p)
{
    int bx = blockIdx.x, tid = threadIdx.x;
    if (bx < 44) {
        __shared__ ushort st[32][130];   // 32 d-rows x 128 n, padded
        const float* src;
        const float* bias;
        ushort* dstbase;
        int kt;
        if (bx < 40) {                   // W1: e = bx>>2, kt = bx&3
            int e = bx >> 2;
            kt = bx & 3;
            src = W1 + (e * D_DIM + kt * 32) * H_DIM;
            bias = b1 + e * H_DIM;
            dstbase = W1p + e * (H_DIM * DP);
        } else {                         // Wc1: kt = bx-40
            kt = bx - 40;
            src = Wc1 + kt * 32 * H_DIM;
            bias = bc1;
            dstbase = Wc1p;
        }
        int dmax = D_DIM - kt * 32;      // 32,32,32,30
#pragma unroll
        for (int p = 0; p < 16; ++p) {
            int idx = p * 256 + tid;
            int dd = idx >> 7, n = idx & 127;
            float v;
            if (dd < dmax)                    v = src[dd * H_DIM + n];   // coalesced in n
            else if (kt == 3 && dd == 30)     v = bias[n];               // bias row (k=126)
            else                              v = 0.f;                   // k=127 pad
            st[dd][n] = f2bf(v);
        }
        __syncthreads();
#pragma unroll
        for (int p = 0; p < 16; ++p) {
            int idx = p * 256 + tid;
            int dd = idx >> 7, n = idx & 127;
            // frag position: nt=n>>4, lm=n&15, lq=dd>>3, j=dd&7
            dstbase[((n >> 4) * 4 + kt) * 512 + ((dd >> 3) * 16 + (n & 15)) * 8 + (dd & 7)]
                = st[dd][n];
        }
    } else {
        // W2 packed as 16x16x16 B-frags: tile kk (k = kk*16 + 4*lq + j), col = lm
        int i = (bx - 44) * 256 + tid;   // [0, 20480)
        int e   = i >> 11;
        int rem = i & 2047;
        int kk  = rem >> 8;
        int idx = rem & 255;
        int l = idx >> 2, j = idx & 3;
        int lq = l >> 4, lm = l & 15;
        W2p[i] = f2bf(W2[(e * H_DIM + kk * 16 + lq * 4 + j) * N_ACT + lm]);
    }
}

// ---------------- kernel 1: natural-order fused MoE + critic ------------------
// R9 configuration restored verbatim — the empirical session optimum (132.1 us
// total; VGPR 52, zero spill). Each block owns 256 CONTIGUOUS tokens (coalesced
// obs -> 64KB swizzled LDS); local bucket -> per-expert TILE PAIRS (32 tokens):
// each W1/W2 fragment read from L2 feeds TWO independent MFMA chains. All
// perturbations tried (smaller tile R8, reg-pipelining R10, 16-wave block R11,
// tighter bounds R1/R6, permuted layouts R5) regressed 4-40 us.
__global__ __launch_bounds__(512, 4) void moe_kernel(
    const float* __restrict__ obs, const int* __restrict__ pick,
    const int* __restrict__ hete_type, const int* __restrict__ gp_sel,
    const float* __restrict__ b2, const float* __restrict__ bc2,
    const ushort* __restrict__ W1p, const ushort* __restrict__ W2p,
    const ushort* __restrict__ Wc1p, const float* __restrict__ Wc2,
    float* __restrict__ out)
{
    __shared__ __align__(16) ushort xa[BTOK * 128];   // 64KB swizzled bf16 rows
    __shared__ short map[576];                        // padded slot -> local token
    __shared__ short jexp[24];                        // job -> expert
    __shared__ short jtb[24];                         // job -> slot base (pair = 32 slots)
    __shared__ int lc[16], lbase[16];
    __shared__ int nj_tot;

    const int bx  = blockIdx.x;
    const int tid = threadIdx.x;
    const int gbase = bx * BTOK;

    if (tid < 16) lc[tid] = 0;
    for (int i = tid; i < 576; i += 512) map[i] = -1;
    __syncthreads();

    // ---- local bucket count (threads 0..255, one token each) ----
    int mye = 0, myloc = 0;
    if (tid < BTOK) {
        mye = pick[gbase + tid];
        myloc = atomicAdd(&lc[mye], 1);
    }

    // ---- stage obs -> LDS bf16, granule-swizzled; fully coalesced global ----
#pragma unroll
    for (int p = 0; p < 8; ++p) {
        int idx = p * 512 + tid;
        if (idx < BTOK * 15) {
            int r = idx / 15, g = idx - r * 15;
            const float* s = obs + (size_t)(gbase + r) * RAWOB + g * 8;
            float4 u0 = *(const float4*)(const void*)s;
            float4 u1 = *(const float4*)(const void*)(s + 4);
            u16x8 t;
            t[0] = f2bf(u0.x); t[1] = f2bf(u0.y); t[2] = f2bf(u0.z); t[3] = f2bf(u0.w);
            t[4] = f2bf(u1.x); t[5] = f2bf(u1.y); t[6] = f2bf(u1.z); t[7] = f2bf(u1.w);
            *(u16x8*)(void*)(xa + r * 128 + (g ^ (r & 15)) * 8) = t;
        }
    }
    // augment granule 15: [hete_type, gp_obs(5), 1.0 (bias k=126), 0]
    if (tid < BTOK) {
        int tok = gbase + tid;
        int ht = hete_type[tok];
        int tt = tok >> 6;                  // token / A_DIM
        u16x8 t;
        t[0] = f2bf((float)ht);
#pragma unroll
        for (int q = 0; q < N_TP; ++q) {
            float g = (q == ht) ? -1.0f : (float)gp_sel[tt * N_TP + q];
            t[1 + q] = f2bf(g);
        }
        t[6] = (ushort)0x3F80;              // 1.0 -> picks up bias row 126
        t[7] = 0;
        *(u16x8*)(void*)(xa + tid * 128 + (15 ^ (tid & 15)) * 8) = t;
    }
    __syncthreads();

    // ---- serial job layout: pair-of-tiles (32 slots) per job ----
    if (tid == 0) {
        int pb = 0, nj = 0;
#pragma unroll
        for (int e = 0; e < E_EXP; ++e) {
            lbase[e] = pb;
            int ntile = (lc[e] + 15) >> 4;          // tiles of 16
            int npair = (ntile + 1) >> 1;           // pad odd -> pair
            for (int k = 0; k < npair; ++k) {
                jexp[nj] = (short)e;
                jtb[nj]  = (short)(pb + k * 32);
                ++nj;
            }
            pb += npair * 32;
        }
        nj_tot = nj;
    }
    __syncthreads();
    if (tid < BTOK) map[lbase[mye] + myloc] = (short)tid;
    __syncthreads();

    const int w = tid >> 6;
    const int l = tid & 63;
    const int lm = l & 15;
    const int lq = l >> 4;
    const float bcv = bc2[0];

    // ---- expert path: waves grab PAIR jobs round-robin; weights from L2 ----
    const int NJ = nj_tot;
    for (int i = w; i < NJ; i += 8) {
        const int e  = jexp[i];
        const int tb = jtb[i];
        const int m0 = map[tb + lm];
        const int m1 = map[tb + 16 + lm];
        const int row0 = m0 < 0 ? 0 : m0;
        const int row1 = m1 < 0 ? 0 : m1;
        bh8 a0[4], a1[4];
#pragma unroll
        for (int kt = 0; kt < 4; ++kt) {
            int g = kt * 4 + lq;
            a0[kt] = *(const bh8*)(const void*)(xa + row0 * 128 + (g ^ (row0 & 15)) * 8);
            a1[kt] = *(const bh8*)(const void*)(xa + row1 * 128 + (g ^ (row1 & 15)) * 8);
        }
        const ushort* w1e = W1p + e * (H_DIM * DP);
        const ushort* w2e = W2p + e * 2048;
        const float bb = b2[e * N_ACT + lm];
        f32x4 y0 = (f32x4){0.f, 0.f, 0.f, 0.f};
        f32x4 y1 = (f32x4){0.f, 0.f, 0.f, 0.f};
#pragma unroll
        for (int nt = 0; nt < 8; ++nt) {
            f32x4 ae0 = (f32x4){0.f, 0.f, 0.f, 0.f}, ae1 = ae0;
#pragma unroll
            for (int kt = 0; kt < 4; ++kt) {
                bh8 wf = *(const bh8*)(const void*)(w1e + (nt * 4 + kt) * 512 + l * 8);
                ae0 = mfma16(wf, a0[kt], ae0);          // two independent chains
                ae1 = mfma16(wf, a1[kt], ae1);          // per weight fragment
            }
            u16x4 hp0, hp1;
#pragma unroll
            for (int r = 0; r < 4; ++r) {
                hp0[r] = f2bf(fmaxf(ae0[r], 0.f));
                hp1[r] = f2bf(fmaxf(ae1[r], 0.f));
            }
            s16x4 w2f = *(const s16x4*)(const void*)(w2e + nt * 256 + l * 4);
            y0 = mfma16k16(__builtin_bit_cast(s16x4, hp0), w2f, y0);
            y1 = mfma16k16(__builtin_bit_cast(s16x4, hp1), w2f, y1);
        }
#pragma unroll
        for (int r = 0; r < 4; ++r) {
            int s0 = map[tb + lq * 4 + r];
            if (s0 >= 0) out[(size_t)(gbase + s0) * N_ACT + lm] = y0[r] + bb;
            int s1 = map[tb + 16 + lq * 4 + r];
            if (s1 >= 0) out[(size_t)(gbase + s1) * N_ACT + lm] = y1[r] + bb;
        }
    }

    // ---- critic: natural-order rows, 2 m-frags per Wc1 fragment, all waves ----
    {
        const int r0 = w * 32;
        const int row0 = r0 + lm, row1 = r0 + 16 + lm;
        bh8 a0[4], a1[4];
#pragma unroll
        for (int kt = 0; kt < 4; ++kt) {
            int g = kt * 4 + lq;
            a0[kt] = *(const bh8*)(const void*)(xa + row0 * 128 + (g ^ (row0 & 15)) * 8);
            a1[kt] = *(const bh8*)(const void*)(xa + row1 * 128 + (g ^ (row1 & 15)) * 8);
        }
        float p0 = 0.f, p1 = 0.f;
#pragma unroll
        for (int nt = 0; nt < 8; ++nt) {
            f32x4 c0 = (f32x4){0.f,0.f,0.f,0.f}, c1 = c0;
#pragma unroll
            for (int kt = 0; kt < 4; ++kt) {
                bh8 wf = *(const bh8*)(const void*)(Wc1p + (nt * 4 + kt) * 512 + l * 8);
                c0 = mfma16(wf, a0[kt], c0);
                c1 = mfma16(wf, a1[kt], c1);
            }
            const float4 wc = *(const float4*)(const void*)(Wc2 + nt * 16 + lq * 4);
            p0 += fmaxf(c0[0], 0.f) * wc.x + fmaxf(c0[1], 0.f) * wc.y
                + fmaxf(c0[2], 0.f) * wc.z + fmaxf(c0[3], 0.f) * wc.w;
            p1 += fmaxf(c1[0], 0.f) * wc.x + fmaxf(c1[1], 0.f) * wc.y
                + fmaxf(c1[2], 0.f) * wc.z + fmaxf(c1[3], 0.f) * wc.w;
        }
        // lane (lq,lm) holds token's partial over its n-subset; sum over lq
        p0 += __shfl_xor(p0, 16, 64); p0 += __shfl_xor(p0, 32, 64);
        p1 += __shfl_xor(p1, 16, 64); p1 += __shfl_xor(p1, 32, 64);
        if (lq == 0) {
            out[LOGITS_SZ + gbase + row0] = p0 + bcv;
            out[LOGITS_SZ + gbase + row1] = p1 + bcv;
        }
    }
}

extern "C" void kernel_launch(void* const* d_in, const int* in_sizes, int n_in,
                              void* d_out, int out_size, void* d_ws, size_t ws_size,
                              hipStream_t stream) {
    const float* obs  = (const float*)d_in[0];
    const int*   pick = (const int*)d_in[1];
    const int*   htyp = (const int*)d_in[2];
    const int*   gp   = (const int*)d_in[3];
    const float* W1   = (const float*)d_in[4];
    const float* b1   = (const float*)d_in[5];
    const float* W2   = (const float*)d_in[6];
    const float* b2   = (const float*)d_in[7];
    const float* Wc1  = (const float*)d_in[8];
    const float* bc1  = (const float*)d_in[9];
    const float* Wc2  = (const float*)d_in[10];
    const float* bc2  = (const float*)d_in[11];
    float* out = (float*)d_out;

    ushort* W1p  = (ushort*)d_ws;
    ushort* W2p  = W1p + W1P_N;
    ushort* Wc1p = W2p + W2P_N;

    prep_kernel<<<PB_BLOCKS, 256, 0, stream>>>(
        W1, W2, Wc1, b1, bc1, W1p, W2p, Wc1p);
    moe_kernel<<<NBLK, 512, 0, stream>>>(
        obs, pick, htyp, gp, b2, bc2,
        W1p, W2p, Wc1p, Wc2, out);
}